// Round 10
// baseline (5412914.453 us; speedup 1.0000x reference)
//
#include <hip/hip_runtime.h>
#include <stdint.h>

#define T_ 50

typedef float f32x4 __attribute__((ext_vector_type(4)));
typedef short s16x8 __attribute__((ext_vector_type(8)));

// ---------------- workspace byte offsets ----------------
#define WS_WIH   0u          // [4cg][256 col][256 k] bf16
#define WS_WHH   524288u
#define WS_WINIT 1048576u    // [4cg][128 col][256 k]
#define WS_WFC   1310720u    // [4cg][64 col][256 k]
#define WS_GPAD  1441792u    // [32][32] bf16 zero-padded G
#define WS_FLG   1443840u    // [64 b][16] u32 flag lines (16 KB)
#define WS_GH    1460224u    // [64 b][2 parity][24 node][256 unit] u16 (1.5 MB)
#define WS_BOOT  3033088u    // cnt[8] @0, done @8, claimed[256] @16, xcdtab[256] @272 (u32 idx)
#define WS_NEED  3037184u

// ---------------- LDS byte offsets (dynamic, 160448 B) ----------------
#define L_WHH  0             // [256][256] bf16 swizzled           131072
#define L_A2   131072        // [24][256] bf16 swizzled (Gx)        12288
#define L_XL   143360        // [24][260] bf16 x_t tile             12480
#define L_ZR   155840        // [256] bf16 zero row                   512
#define L_HST  156352        // [64 unit][32 node] bf16 h stage      4096
#define L_TOT  160448

__device__ __forceinline__ f32x4 mfma16(s16x8 a, s16x8 b, f32x4 c){
  return __builtin_amdgcn_mfma_f32_16x16x32_bf16(a, b, c, 0, 0, 0);
}
__device__ __forceinline__ uint32_t bfbits(float f){
  uint32_t u = __builtin_bit_cast(uint32_t, f);
  u += 0x7FFFu + ((u >> 16) & 1u);   // RNE
  return u >> 16;
}
__device__ __forceinline__ uint32_t pk2bf(float lo, float hi){
  return bfbits(lo) | (bfbits(hi) << 16);
}
#define LOG2E 1.4426950408889634f
__device__ __forceinline__ float fexp2(float x){ return __builtin_amdgcn_exp2f(x); }
__device__ __forceinline__ float frcp_(float x){ return __builtin_amdgcn_rcpf(x); }
__device__ __forceinline__ float fsig(float x){ return frcp_(1.f + fexp2(-LOG2E * x)); }
__device__ __forceinline__ float ftanh_(float x){ return 1.f - 2.f * frcp_(1.f + fexp2(2.f * LOG2E * x)); }

// ---------------- prep: weight layout conversion + control clear ----------------
__global__ void prep_kernel(const float* __restrict__ G,
                            const float* __restrict__ Wih, const float* __restrict__ Whh,
                            const float* __restrict__ Wh1, const float* __restrict__ Wh2,
                            const float* __restrict__ Wfc, uint8_t* __restrict__ ws)
{
  const int tid = blockIdx.x * blockDim.x + threadIdx.x;
  const int nth = gridDim.x * blockDim.x;
  uint16_t* wih = (uint16_t*)(ws + WS_WIH);
  uint16_t* whh = (uint16_t*)(ws + WS_WHH);
  uint16_t* wini= (uint16_t*)(ws + WS_WINIT);
  uint16_t* wfc = (uint16_t*)(ws + WS_WFC);
  uint16_t* gp  = (uint16_t*)(ws + WS_GPAD);
  uint32_t* flg = (uint32_t*)(ws + WS_FLG);
  uint32_t* boot= (uint32_t*)(ws + WS_BOOT);

  for (int i = tid; i < 262144; i += nth){
    int cg = i >> 16, c = (i >> 8) & 255, k = i & 255;
    int row = (c >> 6)*256 + 64*cg + (c & 63);
    wih[i] = (uint16_t)bfbits(Wih[row*256 + k]);
    whh[i] = (uint16_t)bfbits(Whh[row*256 + k]);
  }
  for (int i = tid; i < 131072; i += nth){
    int cg = i >> 15, c = (i >> 8) & 127, k = i & 255;
    float v = (c < 64) ? Wh1[(64*cg + c)*256 + k] : Wh2[(64*cg + c - 64)*256 + k];
    wini[i] = (uint16_t)bfbits(v);
  }
  for (int i = tid; i < 65536; i += nth){
    int cg = i >> 14, c = (i >> 8) & 63, k = i & 255;
    wfc[i] = (uint16_t)bfbits(Wfc[(64*cg + c)*256 + k]);
  }
  for (int i = tid; i < 1024; i += nth){
    int n = i >> 5, m = i & 31;
    gp[i] = (n < 24 && m < 24) ? (uint16_t)bfbits(G[n*24 + m]) : (uint16_t)0;
  }
  for (int i = tid; i < 4096; i += nth) flg[i] = 0;    // flags gate GH validity
  for (int i = tid; i < 1024; i += nth) boot[i] = 0;   // claim counters/tables
}

// ---------------- persistent cooperative encoder ----------------
// grid 256; each WG self-assigns (batch, cg) from per-XCD pools so a batch's
// 4 WGs share an XCD -> exchange via XCD-local L2 (sc0). Fallback: agent scope.
__global__ void __launch_bounds__(512, 1)
encoder_kernel(const float* __restrict__ x, uint8_t* __restrict__ ws,
               float* __restrict__ out,
               const float* __restrict__ bih, const float* __restrict__ bhh,
               const float* __restrict__ bh1, const float* __restrict__ bh2,
               const float* __restrict__ bfc)
{
  extern __shared__ uint8_t smem[];
  uint16_t* WHHL = (uint16_t*)(smem + L_WHH);
  uint16_t* A2   = (uint16_t*)(smem + L_A2);
  uint16_t* XL   = (uint16_t*)(smem + L_XL);
  uint16_t* ZR   = (uint16_t*)(smem + L_ZR);
  uint16_t* HST  = (uint16_t*)(smem + L_HST);
  __shared__ int sh_boot[3];

  const int tid = threadIdx.x;

  // ---- bootstrap: claim (batch, cg) from this XCD's pool ----
  if (tid == 0){
    int xcc;
    asm volatile("s_getreg_b32 %0, hwreg(HW_REG_XCC_ID)" : "=s"(xcc));
    xcc &= 7;
    uint32_t* cnt     = (uint32_t*)(ws + WS_BOOT);
    uint32_t* done    = cnt + 8;
    uint32_t* claimed = cnt + 16;
    uint32_t* xcdtab  = cnt + 272;
    int slot = -1;
    uint32_t s = atomicAdd(&cnt[xcc], 1u);
    if (s < 32u){
      slot = xcc*32 + (int)s;
      atomicExch(&claimed[slot], 1u);
      asm volatile("s_waitcnt vmcnt(0)" ::: "memory");  // claim visible before done++
    }
    atomicAdd(done, 1u);
    if (slot < 0){                      // fallback (not expected: 1 WG/CU => 32/XCD)
      int guard = 0;
      while (__hip_atomic_load(done, __ATOMIC_RELAXED, __HIP_MEMORY_SCOPE_AGENT) < 256u){
        __builtin_amdgcn_s_sleep(8);
        if (++guard > 100000000) break;
      }
      for (int i = 0; i < 256 && slot < 0; i++)
        if (atomicCAS(&claimed[i], 0u, 1u) == 0u) slot = i;
    }
    int bb = (slot >> 5)*8 + ((slot & 31) >> 2);
    int cc = slot & 3;
    __hip_atomic_store(&xcdtab[bb*4+cc], (uint32_t)(xcc+1),
                       __ATOMIC_RELAXED, __HIP_MEMORY_SCOPE_AGENT);
    uint32_t xs[4]; bool all; int guard = 0;
    do {
      all = true;
      #pragma unroll
      for (int j = 0; j < 4; j++){
        xs[j] = __hip_atomic_load(&xcdtab[bb*4+j], __ATOMIC_RELAXED, __HIP_MEMORY_SCOPE_AGENT);
        all = all && (xs[j] != 0u);
      }
      if (++guard > 100000000) break;
    } while (!all);
    sh_boot[0] = bb; sh_boot[1] = cc;
    sh_boot[2] = (xs[0]==xs[1] && xs[1]==xs[2] && xs[2]==xs[3]) ? 1 : 0;
  }
  __syncthreads();
  const int  b  = sh_boot[0];
  const int  cg = sh_boot[1];
  const bool sx = sh_boot[2] != 0;     // same-XCD: L2-coherent exchange

  const int w   = tid >> 6;
  const int l   = tid & 63;
  const int l15 = l & 15;
  const int g   = l >> 4;
  const int Mt  = w >> 2;
  const int ns  = w & 3;
  const int ul  = ns*16 + l15;
  const int ug  = 64*cg + ul;

  const uint16_t* WIH  = (const uint16_t*)(ws + WS_WIH)   + (size_t)cg*65536;
  const uint16_t* WINI = (const uint16_t*)(ws + WS_WINIT) + (size_t)cg*32768;
  const uint16_t* WFC  = (const uint16_t*)(ws + WS_WFC)   + (size_t)cg*16384;
  const uint16_t* GP   = (const uint16_t*)(ws + WS_GPAD);
  uint32_t* flgB = (uint32_t*)(ws + WS_FLG) + b*64;
  uint32_t* flgW = flgB + cg*16;
  uint16_t* GhT  = (uint16_t*)(ws + WS_GH) + (size_t)b*12288;  // 2 parity x [24][256]

  // ---- load W_hh slice into LDS (swizzled)
  {
    const uint8_t* src = ws + WS_WHH + (size_t)cg*131072;
    for (int i = tid*8; i < 65536; i += 4096){
      uint4 v = *(const uint4*)(src + (size_t)i*2);
      int col = i >> 8, k0 = i & 255;
      *(uint4*)&WHHL[col*256 + (k0 ^ ((col&7)<<3))] = v;
    }
  }
  for (int i = tid; i < 256;  i += 512) ZR[i] = 0;
  for (int i = tid; i < 2048; i += 512) HST[i] = 0;   // k-pad rows vs NaN

  s16x8 gfragM = *(const s16x8*)&GP[(Mt*16 + l15)*32 + g*8];

  const float bb0 = bih[ug]     + bhh[ug];
  const float bb1 = bih[256+ug] + bhh[256+ug];
  const float bb2 = bih[512+ug] + bhh[512+ug];
  const float bb3 = bih[768+ug] + bhh[768+ug];
  const float bh1l = bh1[ug], bh2l = bh2[ug], bfcl = bfc[ug];

  const int arow = Mt*16 + l15;
  const int crow = (arow < 24) ? arow : 23;
  const uint16_t* a2row = (arow < 24) ? (A2 + arow*256) : ZR;
  const int sw = (arow < 24) ? ((arow & 7) << 3) : 0;

  auto xld_issue = [&](const float* xt, f32x4 xv[3]){
    #pragma unroll
    for (int p = 0; p < 3; p++)
      xv[p] = *(const f32x4*)(xt + tid*4 + p*2048);
  };
  auto xld_write = [&](const f32x4 xv[3]){
    #pragma unroll
    for (int p = 0; p < 3; p++){
      int e = tid*4 + p*2048;
      int m = e >> 8, f = e & 255;
      uint2 pk; pk.x = pk2bf(xv[p][0], xv[p][1]); pk.y = pk2bf(xv[p][2], xv[p][3]);
      *(uint2*)&XL[m*260 + f] = pk;
    }
  };

  auto gx_stage = [&](){
    #pragma unroll
    for (int jt = 0; jt < 4; jt++){
      int f = (jt*4 + ns)*16 + l15;
      s16x8 bfrag = (s16x8){0,0,0,0,0,0,0,0};
      if (g < 3){
        #pragma unroll
        for (int j = 0; j < 8; j++)
          bfrag[j] = (short)XL[(g*8 + j)*260 + f];
      }
      f32x4 zz = {0.f,0.f,0.f,0.f};
      f32x4 gx = mfma16(gfragM, bfrag, zz);
      int n0 = Mt*16 + g*4;
      if (n0 < 24){
        uint32_t a01 = pk2bf(gx[0], gx[1]), a23 = pk2bf(gx[2], gx[3]);
        A2[(n0  )*256 + (f ^ (((n0  )&7)<<3))] = (uint16_t)a01;
        A2[(n0+1)*256 + (f ^ (((n0+1)&7)<<3))] = (uint16_t)(a01>>16);
        A2[(n0+2)*256 + (f ^ (((n0+2)&7)<<3))] = (uint16_t)a23;
        A2[(n0+3)*256 + (f ^ (((n0+3)&7)<<3))] = (uint16_t)(a23>>16);
      }
    }
  };

  // Gh fragments: 8 x dwordx4 direct to registers, coherent per sx mode.
  auto ghload = [&](int parity, s16x8 af[8]){
    const uint16_t* base = GhT + parity*6144 + crow*256 + g*8;
    uint4 f0,f1,f2,f3,f4,f5,f6,f7;
    if (sx){
      asm volatile(
        "global_load_dwordx4 %0, %8, off sc0\n\t"
        "global_load_dwordx4 %1, %8, off offset:64 sc0\n\t"
        "global_load_dwordx4 %2, %8, off offset:128 sc0\n\t"
        "global_load_dwordx4 %3, %8, off offset:192 sc0\n\t"
        "global_load_dwordx4 %4, %8, off offset:256 sc0\n\t"
        "global_load_dwordx4 %5, %8, off offset:320 sc0\n\t"
        "global_load_dwordx4 %6, %8, off offset:384 sc0\n\t"
        "global_load_dwordx4 %7, %8, off offset:448 sc0\n\t"
        "s_waitcnt vmcnt(0)"
        : "=&v"(f0),"=&v"(f1),"=&v"(f2),"=&v"(f3),
          "=&v"(f4),"=&v"(f5),"=&v"(f6),"=&v"(f7)
        : "v"(base) : "memory");
    } else {
      asm volatile(
        "global_load_dwordx4 %0, %8, off sc0 sc1\n\t"
        "global_load_dwordx4 %1, %8, off offset:64 sc0 sc1\n\t"
        "global_load_dwordx4 %2, %8, off offset:128 sc0 sc1\n\t"
        "global_load_dwordx4 %3, %8, off offset:192 sc0 sc1\n\t"
        "global_load_dwordx4 %4, %8, off offset:256 sc0 sc1\n\t"
        "global_load_dwordx4 %5, %8, off offset:320 sc0 sc1\n\t"
        "global_load_dwordx4 %6, %8, off offset:384 sc0 sc1\n\t"
        "global_load_dwordx4 %7, %8, off offset:448 sc0 sc1\n\t"
        "s_waitcnt vmcnt(0)"
        : "=&v"(f0),"=&v"(f1),"=&v"(f2),"=&v"(f3),
          "=&v"(f4),"=&v"(f5),"=&v"(f6),"=&v"(f7)
        : "v"(base) : "memory");
    }
    af[0] = __builtin_bit_cast(s16x8, f0); af[1] = __builtin_bit_cast(s16x8, f1);
    af[2] = __builtin_bit_cast(s16x8, f2); af[3] = __builtin_bit_cast(s16x8, f3);
    af[4] = __builtin_bit_cast(s16x8, f4); af[5] = __builtin_bit_cast(s16x8, f5);
    af[6] = __builtin_bit_cast(s16x8, f6); af[7] = __builtin_bit_cast(s16x8, f7);
  };

  auto wait_for = [&](uint32_t target){
    if (tid < 4){
      const uint32_t* fp = flgB + tid*16;
      uint32_t v; int guard = 0;
      for (;;){
        if (sx) asm volatile("global_load_dword %0, %1, off sc0\n\ts_waitcnt vmcnt(0)"
                             : "=v"(v) : "v"(fp) : "memory");
        else    asm volatile("global_load_dword %0, %1, off sc0 sc1\n\ts_waitcnt vmcnt(0)"
                             : "=v"(v) : "v"(fp) : "memory");
        if (v >= target) break;
        __builtin_amdgcn_s_sleep(1);
        if (++guard > 50000000) break;   // loud fail (wrong result), no hang
      }
    }
    __syncthreads();
  };

  // publish: h -> HST -> (P1) -> Gh MFMA -> 4 short stores -> vmcnt -> (P3) -> flag
  auto do_publish = [&](const float hv[4], int parity, uint32_t flagval){
    int n0 = Mt*16 + g*4;
    if (n0 < 24){
      uint2 p; p.x = pk2bf(hv[0], hv[1]); p.y = pk2bf(hv[2], hv[3]);
      *(uint2*)&HST[ul*32 + n0] = p;
    }
    __syncthreads();                     // P1: HST complete (also fences A2/XL)
    s16x8 hb = *(const s16x8*)&HST[ul*32 + g*8];
    f32x4 zz = {0.f,0.f,0.f,0.f};
    f32x4 gh = mfma16(gfragM, hb, zz);
    uint16_t* gd = GhT + parity*6144;
    if (n0 < 24){
      #pragma unroll
      for (int r = 0; r < 4; r++){
        uint32_t hv16 = bfbits(gh[r]);
        const uint16_t* p = gd + (n0+r)*256 + ug;
        if (sx) asm volatile("global_store_short %0, %1, off sc0" :: "v"(p), "v"(hv16) : "memory");
        else    asm volatile("global_store_short %0, %1, off sc0 sc1" :: "v"(p), "v"(hv16) : "memory");
      }
    }
    asm volatile("s_waitcnt vmcnt(0)" ::: "memory");
    __syncthreads();                     // P3: all waves' stores complete
    if (tid == 0){
      uint32_t fv = flagval;
      if (sx) asm volatile("global_store_dword %0, %1, off sc0" :: "v"(flgW), "v"(fv) : "memory");
      else    asm volatile("global_store_dword %0, %1, off sc0 sc1" :: "v"(flgW), "v"(fv) : "memory");
    }
  };

  float cst[4];
  f32x4 zacc[4];
  const float* xb = x + (size_t)b*T_*6144;

  // ---------- init: x0 -> XL -> Gx0 -> h0/c0/z0; publish k=1 (parity 1) ----------
  {
    f32x4 xv[3];
    xld_issue(xb, xv);
    xld_write(xv);
  }
  __syncthreads();                                     // I0
  gx_stage();
  __syncthreads();                                     // I1
  {
    f32x4 h0a = {0.f,0.f,0.f,0.f}, c0a = {0.f,0.f,0.f,0.f};
    #pragma unroll
    for (int j = 0; j < 4; j++) zacc[j] = (f32x4){0.f,0.f,0.f,0.f};
    #pragma unroll
    for (int ks = 0; ks < 8; ks++){
      const int kk = ks*32 + g*8;
      s16x8 a  = *(const s16x8*)&a2row[kk ^ sw];
      s16x8 b1 = *(const s16x8*)&WINI[ul*256 + kk];
      s16x8 b2 = *(const s16x8*)&WINI[(64+ul)*256 + kk];
      h0a = mfma16(a, b1, h0a);
      c0a = mfma16(a, b2, c0a);
      #pragma unroll
      for (int j = 0; j < 4; j++){
        s16x8 bz = *(const s16x8*)&WIH[((j*4+ns)*16 + l15)*256 + kk];
        zacc[j] = mfma16(a, bz, zacc[j]);
      }
    }
    float hv0[4];
    #pragma unroll
    for (int r = 0; r < 4; r++){
      cst[r] = c0a[r] + bh2l;
      hv0[r] = h0a[r] + bh1l;
    }
    do_publish(hv0, 1, 1u);
  }
  {                                                    // stage Gx[1]
    f32x4 xv[3];
    xld_issue(xb + 6144, xv);
    xld_write(xv);
    __syncthreads();                                   // X0
    gx_stage();
  }

  // ---------- recurrence ----------
  for (int t = 0; t < T_; t++){
    wait_for((uint32_t)(t+1));
    s16x8 af[8];
    ghload((t+1)&1, af);

    f32x4 uacc[4];
    #pragma unroll
    for (int j = 0; j < 4; j++) uacc[j] = zacc[j];
    #pragma unroll
    for (int ks = 0; ks < 8; ks++){
      const int kk = ks*32 + g*8;
      #pragma unroll
      for (int j = 0; j < 4; j++){
        int col = (j*4+ns)*16 + l15;
        s16x8 bf = *(const s16x8*)&WHHL[col*256 + (kk ^ ((col&7)<<3))];
        uacc[j] = mfma16(af[ks], bf, uacc[j]);
      }
    }
    float hv[4];
    #pragma unroll
    for (int r = 0; r < 4; r++){
      float ig = fsig  (uacc[0][r] + bb0);
      float fg = fsig  (uacc[1][r] + bb1);
      float gg = ftanh_(uacc[2][r] + bb2);
      float og = fsig  (uacc[3][r] + bb3);
      float c  = fg*cst[r] + ig*gg;
      cst[r] = c;
      hv[r] = og*ftanh_(c);
    }
    do_publish(hv, t & 1, (uint32_t)(t+2));

    // slack: x[t+2] issue, z[t+1] GEMM, restage XL/A2
    if (t+1 < T_){
      int tn = (t+2 < T_) ? (t+2) : (T_-1);
      f32x4 xv[3];
      xld_issue(xb + (size_t)tn*6144, xv);
      #pragma unroll
      for (int j = 0; j < 4; j++) zacc[j] = (f32x4){0.f,0.f,0.f,0.f};
      #pragma unroll
      for (int ks = 0; ks < 8; ks++){
        const int kk = ks*32 + g*8;
        s16x8 a = *(const s16x8*)&a2row[kk ^ sw];
        #pragma unroll
        for (int j = 0; j < 4; j++){
          s16x8 bf = *(const s16x8*)&WIH[((j*4+ns)*16 + l15)*256 + kk];
          zacc[j] = mfma16(a, bf, zacc[j]);
        }
      }
      __syncthreads();                                 // S1
      xld_write(xv);
      __syncthreads();                                 // X1
      gx_stage();
    }
  }

  // ---------- final: out = tanh(Gh_final . W_fc^T + bfc) ----------
  wait_for((uint32_t)(T_+1));
  {
    s16x8 af[8];
    ghload(1, af);                                     // parity (T-1)&1 = 1
    f32x4 oacc = {0.f,0.f,0.f,0.f};
    #pragma unroll
    for (int ks = 0; ks < 8; ks++){
      const int kk = ks*32 + g*8;
      s16x8 bf = *(const s16x8*)&WFC[ul*256 + kk];
      oacc = mfma16(af[ks], bf, oacc);
    }
    int n0 = Mt*16 + g*4;
    if (n0 < 24){
      #pragma unroll
      for (int r = 0; r < 4; r++)
        out[(size_t)b*6144 + (n0+r)*256 + ug] = ftanh_(oacc[r] + bfcl);
    }
  }
}

extern "C" void kernel_launch(void* const* d_in, const int* in_sizes, int n_in,
                              void* d_out, int out_size, void* d_ws, size_t ws_size,
                              hipStream_t stream)
{
  (void)in_sizes; (void)n_in; (void)out_size;
  if (ws_size < WS_NEED) return;   // loud failure via validation rather than OOB

  const float* x   = (const float*)d_in[0];
  const float* G   = (const float*)d_in[1];
  const float* Wih = (const float*)d_in[2];
  const float* bih = (const float*)d_in[3];
  const float* Whh = (const float*)d_in[4];
  const float* bhh = (const float*)d_in[5];
  const float* Wh1 = (const float*)d_in[6];
  const float* bh1 = (const float*)d_in[7];
  const float* Wh2 = (const float*)d_in[8];
  const float* bh2 = (const float*)d_in[9];
  const float* Wfc = (const float*)d_in[10];
  const float* bfc = (const float*)d_in[11];
  uint8_t* ws = (uint8_t*)d_ws;
  float* outp = (float*)d_out;

  hipLaunchKernelGGL(prep_kernel, dim3(256), dim3(256), 0, stream,
                     G, Wih, Whh, Wh1, Wh2, Wfc, ws);

  hipFuncSetAttribute((const void*)encoder_kernel,
                      hipFuncAttributeMaxDynamicSharedMemorySize, L_TOT);
  void* args[] = {(void*)&x, (void*)&ws, (void*)&outp,
                  (void*)&bih, (void*)&bhh, (void*)&bh1, (void*)&bh2, (void*)&bfc};
  hipLaunchCooperativeKernel((const void*)encoder_kernel, dim3(256), dim3(512),
                             args, L_TOT, stream);
}

// Round 11
// 1578.735 us; speedup vs baseline: 3428.6409x; 3428.6409x over previous
//
#include <hip/hip_runtime.h>
#include <stdint.h>

#define T_ 50

typedef float f32x2 __attribute__((ext_vector_type(2)));
typedef float f32x4 __attribute__((ext_vector_type(4)));
typedef short s16x8 __attribute__((ext_vector_type(8)));

// ---------------- workspace byte offsets ----------------
#define WS_WIH   0u          // [1024 n][256 k] bf16 (natural row order)
#define WS_WHH   524288u     // [1024 n][256 k] bf16
#define WS_WINIT 1048576u    // [512][256]: rows 0-255 W_h1, 256-511 W_h2
#define WS_WFC   1310720u    // [256][256] bf16
#define WS_GPAD  1441792u    // [32][32] bf16 zero-padded G
#define WS_NEED  1443840u

// ---------------- LDS byte offsets (dynamic, 78592 B) ----------------
#define L_A1   0             // [24][256] bf16 swizzled (Gh)        12288*2
#define L_A2   24576         // [24][256] bf16 swizzled (Gx)
#define L_XL   49152         // [24][260] bf16 x tile               12480
#define L_ZR   61696         // [256] bf16 zero row                   512
#define L_HST  62208         // [256 unit][32 node] bf16 h stage    16384
#define L_TOT  78592

__device__ __forceinline__ f32x4 mfma16(s16x8 a, s16x8 b, f32x4 c){
  return __builtin_amdgcn_mfma_f32_16x16x32_bf16(a, b, c, 0, 0, 0);
}
__device__ __forceinline__ uint32_t bfbits(float f){
  uint32_t u = __builtin_bit_cast(uint32_t, f);
  u += 0x7FFFu + ((u >> 16) & 1u);   // RNE
  return u >> 16;
}
__device__ __forceinline__ uint32_t pk2bf(float lo, float hi){
  return bfbits(lo) | (bfbits(hi) << 16);
}
#define LOG2E 1.4426950408889634f
__device__ __forceinline__ float fexp2(float x){ return __builtin_amdgcn_exp2f(x); }
__device__ __forceinline__ float frcp_(float x){ return __builtin_amdgcn_rcpf(x); }
__device__ __forceinline__ float fsig(float x){ return frcp_(1.f + fexp2(-LOG2E * x)); }
__device__ __forceinline__ float ftanh_(float x){ return 1.f - 2.f * frcp_(1.f + fexp2(2.f * LOG2E * x)); }

// ---------------- prep: f32 -> bf16 weight images ----------------
__global__ void prep_kernel(const float* __restrict__ G,
                            const float* __restrict__ Wih, const float* __restrict__ Whh,
                            const float* __restrict__ Wh1, const float* __restrict__ Wh2,
                            const float* __restrict__ Wfc, uint8_t* __restrict__ ws)
{
  const int tid = blockIdx.x * blockDim.x + threadIdx.x;
  const int nth = gridDim.x * blockDim.x;
  uint16_t* wih = (uint16_t*)(ws + WS_WIH);
  uint16_t* whh = (uint16_t*)(ws + WS_WHH);
  uint16_t* wini= (uint16_t*)(ws + WS_WINIT);
  uint16_t* wfc = (uint16_t*)(ws + WS_WFC);
  uint16_t* gp  = (uint16_t*)(ws + WS_GPAD);

  for (int i = tid; i < 262144; i += nth){
    wih[i] = (uint16_t)bfbits(Wih[i]);
    whh[i] = (uint16_t)bfbits(Whh[i]);
  }
  for (int i = tid; i < 131072; i += nth){
    int n = i >> 8, k = i & 255;
    float v = (n < 256) ? Wh1[n*256 + k] : Wh2[(n-256)*256 + k];
    wini[i] = (uint16_t)bfbits(v);
  }
  for (int i = tid; i < 65536; i += nth)
    wfc[i] = (uint16_t)bfbits(Wfc[i]);
  for (int i = tid; i < 1024; i += nth){
    int n = i >> 5, m = i & 31;
    gp[i] = (n < 24 && m < 24) ? (uint16_t)bfbits(G[n*24 + m]) : (uint16_t)0;
  }
}

// ---------------- one workgroup per batch, 16 waves, no inter-WG sync ----------------
__global__ void __launch_bounds__(1024, 4)
encoder_kernel(const float* __restrict__ x, const uint8_t* __restrict__ ws,
               float* __restrict__ out,
               const float* __restrict__ bih, const float* __restrict__ bhh,
               const float* __restrict__ bh1, const float* __restrict__ bh2,
               const float* __restrict__ bfc)
{
  extern __shared__ uint8_t smem[];
  uint16_t* A1  = (uint16_t*)(smem + L_A1);
  uint16_t* A2  = (uint16_t*)(smem + L_A2);
  uint16_t* XL  = (uint16_t*)(smem + L_XL);
  uint16_t* ZR  = (uint16_t*)(smem + L_ZR);
  uint16_t* HST = (uint16_t*)(smem + L_HST);

  const int tid = threadIdx.x;
  const int b   = blockIdx.x;
  const int w   = tid >> 6;        // wave 0..15
  const int l   = tid & 63;
  const int l15 = l & 15;
  const int g   = l >> 4;
  const int u   = w*16 + l15;      // unit 0..255 (this lane's gate column)

  const uint16_t* WIH  = (const uint16_t*)(ws + WS_WIH);
  const uint16_t* WHH  = (const uint16_t*)(ws + WS_WHH);
  const uint16_t* WINI = (const uint16_t*)(ws + WS_WINIT);
  const uint16_t* WFC  = (const uint16_t*)(ws + WS_WFC);
  const uint16_t* GP   = (const uint16_t*)(ws + WS_GPAD);

  for (int i = tid; i < 256;  i += 1024) ZR[i] = 0;
  for (int i = tid; i < 8192; i += 1024) HST[i] = 0;   // node-pad 24-31 vs NaN

  // G A-fragments for both node tiles
  s16x8 gfragM[2];
  gfragM[0] = *(const s16x8*)&GP[(l15     )*32 + g*8];
  gfragM[1] = *(const s16x8*)&GP[(l15 + 16)*32 + g*8];

  const float bb0 = bih[u]     + bhh[u];
  const float bb1 = bih[256+u] + bhh[256+u];
  const float bb2 = bih[512+u] + bhh[512+u];
  const float bb3 = bih[768+u] + bhh[768+u];
  const float bh1l = bh1[u], bh2l = bh2[u], bfcl = bfc[u];

  // A-fragment row pointers (Mt=0 rows 0-15 valid; Mt=1 rows 16-31, >=24 -> ZR)
  const int r1v = (16 + l15) < 24;
  const uint16_t* a1r[2] = { A1 + l15*256, r1v ? (A1 + (16+l15)*256) : ZR };
  const uint16_t* a2r[2] = { A2 + l15*256, r1v ? (A2 + (16+l15)*256) : ZR };
  const int swz[2] = { (l15 & 7) << 3, r1v ? (((16+l15) & 7) << 3) : 0 };

  // x tile: 6144 f32, 6 per thread as 3x f32x2 (issue-early/write-late)
  auto xld_issue = [&](const float* xt, f32x2 xv[3]){
    #pragma unroll
    for (int p = 0; p < 3; p++)
      xv[p] = *(const f32x2*)(xt + tid*2 + p*2048);
  };
  auto xld_write = [&](const f32x2 xv[3]){
    #pragma unroll
    for (int p = 0; p < 3; p++){
      int e = tid*2 + p*2048;
      int m = e >> 8, f = e & 255;
      *(uint32_t*)&XL[m*260 + f] = pk2bf(xv[p][0], xv[p][1]);
    }
  };

  // Gx[t]: wave's 16-feature column tile, both node tiles -> A2 swizzled
  auto gx_stage = [&](){
    s16x8 bfrag = (s16x8){0,0,0,0,0,0,0,0};
    if (g < 3){
      #pragma unroll
      for (int j = 0; j < 8; j++)
        bfrag[j] = (short)XL[(g*8 + j)*260 + u];
    }
    #pragma unroll
    for (int Mt = 0; Mt < 2; Mt++){
      f32x4 zz = {0.f,0.f,0.f,0.f};
      f32x4 gx = mfma16(gfragM[Mt], bfrag, zz);
      int n0 = Mt*16 + g*4;
      if (n0 < 24){
        uint32_t a01 = pk2bf(gx[0], gx[1]), a23 = pk2bf(gx[2], gx[3]);
        A2[(n0  )*256 + (u ^ (((n0  )&7)<<3))] = (uint16_t)a01;
        A2[(n0+1)*256 + (u ^ (((n0+1)&7)<<3))] = (uint16_t)(a01>>16);
        A2[(n0+2)*256 + (u ^ (((n0+2)&7)<<3))] = (uint16_t)a23;
        A2[(n0+3)*256 + (u ^ (((n0+3)&7)<<3))] = (uint16_t)(a23>>16);
      }
    }
  };

  // Gh from HST -> A1 swizzled (wave's 16-unit column tile)
  auto gh_stage = [&](){
    s16x8 hb = *(const s16x8*)&HST[u*32 + g*8];
    #pragma unroll
    for (int Mt = 0; Mt < 2; Mt++){
      f32x4 zz = {0.f,0.f,0.f,0.f};
      f32x4 gh = mfma16(gfragM[Mt], hb, zz);
      int n0 = Mt*16 + g*4;
      if (n0 < 24){
        uint32_t a01 = pk2bf(gh[0], gh[1]), a23 = pk2bf(gh[2], gh[3]);
        A1[(n0  )*256 + (u ^ (((n0  )&7)<<3))] = (uint16_t)a01;
        A1[(n0+1)*256 + (u ^ (((n0+1)&7)<<3))] = (uint16_t)(a01>>16);
        A1[(n0+2)*256 + (u ^ (((n0+2)&7)<<3))] = (uint16_t)a23;
        A1[(n0+3)*256 + (u ^ (((n0+3)&7)<<3))] = (uint16_t)(a23>>16);
      }
    }
  };

  float cst[2][4];
  f32x4 acc[4][2];                 // [gate][node tile] — z_t, then += Gh.W_hh
  const float* xb = x + (size_t)b * T_ * 6144;

  // ---------- init ----------
  {
    f32x2 xv[3];
    xld_issue(xb, xv);
    xld_write(xv);
  }
  __syncthreads();                 // XL = x0
  gx_stage();                      // -> A2 = Gx0 (A2 "A1 role" here: reuse)
  __syncthreads();
  {
    f32x4 h0a[2] = {{0,0,0,0},{0,0,0,0}}, c0a[2] = {{0,0,0,0},{0,0,0,0}};
    #pragma unroll
    for (int gt = 0; gt < 4; gt++)
      #pragma unroll
      for (int Mt = 0; Mt < 2; Mt++) acc[gt][Mt] = (f32x4){0,0,0,0};
    #pragma unroll 2
    for (int ks = 0; ks < 8; ks++){
      const int kk = ks*32 + g*8;
      s16x8 a0 = *(const s16x8*)&a2r[0][kk ^ swz[0]];
      s16x8 a1 = *(const s16x8*)&a2r[1][kk ^ swz[1]];
      s16x8 b1 = *(const s16x8*)&WINI[u*256 + kk];
      s16x8 b2 = *(const s16x8*)&WINI[(256+u)*256 + kk];
      h0a[0] = mfma16(a0, b1, h0a[0]);  h0a[1] = mfma16(a1, b1, h0a[1]);
      c0a[0] = mfma16(a0, b2, c0a[0]);  c0a[1] = mfma16(a1, b2, c0a[1]);
      #pragma unroll
      for (int gt = 0; gt < 4; gt++){
        s16x8 bz = *(const s16x8*)&WIH[(gt*256 + u)*256 + kk];
        acc[gt][0] = mfma16(a0, bz, acc[gt][0]);
        acc[gt][1] = mfma16(a1, bz, acc[gt][1]);
      }
    }
    #pragma unroll
    for (int Mt = 0; Mt < 2; Mt++){
      int n0 = Mt*16 + g*4;
      float hv[4];
      #pragma unroll
      for (int r = 0; r < 4; r++){
        cst[Mt][r] = c0a[Mt][r] + bh2l;
        hv[r]      = h0a[Mt][r] + bh1l;
      }
      if (n0 < 24){
        uint2 p; p.x = pk2bf(hv[0], hv[1]); p.y = pk2bf(hv[2], hv[3]);
        *(uint2*)&HST[u*32 + n0] = p;
      }
    }
  }
  __syncthreads();                 // HST = h0; Gx0 reads done
  gh_stage();                      // A1 = Gh0
  {
    f32x2 xv[3];
    xld_issue(xb + 6144, xv);      // x1 (latency hides under barrier+writes)
    __syncthreads();               // XL free (x0 consumed)
    xld_write(xv);
  }
  __syncthreads();
  gx_stage();                      // A2 = Gx1
  __syncthreads();                 // A1,A2 ready

  // ---------- recurrence: acc holds z_t at loop top ----------
  for (int t = 0; t < T_; t++){
    // u = z_t + Gh_t . W_hh^T
    #pragma unroll 2
    for (int ks = 0; ks < 8; ks++){
      const int kk = ks*32 + g*8;
      s16x8 a0 = *(const s16x8*)&a1r[0][kk ^ swz[0]];
      s16x8 a1 = *(const s16x8*)&a1r[1][kk ^ swz[1]];
      #pragma unroll
      for (int gt = 0; gt < 4; gt++){
        s16x8 bf = *(const s16x8*)&WHH[(gt*256 + u)*256 + kk];
        acc[gt][0] = mfma16(a0, bf, acc[gt][0]);
        acc[gt][1] = mfma16(a1, bf, acc[gt][1]);
      }
    }
    // LSTM pointwise -> h to HST
    #pragma unroll
    for (int Mt = 0; Mt < 2; Mt++){
      int n0 = Mt*16 + g*4;
      float hv[4];
      #pragma unroll
      for (int r = 0; r < 4; r++){
        float ig = fsig  (acc[0][Mt][r] + bb0);
        float fg = fsig  (acc[1][Mt][r] + bb1);
        float gg = ftanh_(acc[2][Mt][r] + bb2);
        float og = fsig  (acc[3][Mt][r] + bb3);
        float c  = fg*cst[Mt][r] + ig*gg;
        cst[Mt][r] = c;
        hv[r] = og*ftanh_(c);
      }
      if (n0 < 24){
        uint2 p; p.x = pk2bf(hv[0], hv[1]); p.y = pk2bf(hv[2], hv[3]);
        *(uint2*)&HST[u*32 + n0] = p;
      }
    }
    __syncthreads();               // B1: HST done; A1 reads done
    gh_stage();                    // A1 = Gh_{t+1}

    if (t+1 < T_){
      int tn = (t+2 < T_) ? (t+2) : (T_-1);
      f32x2 xv[3];
      xld_issue(xb + (size_t)tn*6144, xv);   // x_{t+2}, hides under z-GEMM
      // z_{t+1} = Gx_{t+1} . W_ih^T
      #pragma unroll
      for (int gt = 0; gt < 4; gt++)
        #pragma unroll
        for (int Mt = 0; Mt < 2; Mt++) acc[gt][Mt] = (f32x4){0,0,0,0};
      #pragma unroll 2
      for (int ks = 0; ks < 8; ks++){
        const int kk = ks*32 + g*8;
        s16x8 a0 = *(const s16x8*)&a2r[0][kk ^ swz[0]];
        s16x8 a1 = *(const s16x8*)&a2r[1][kk ^ swz[1]];
        #pragma unroll
        for (int gt = 0; gt < 4; gt++){
          s16x8 bf = *(const s16x8*)&WIH[(gt*256 + u)*256 + kk];
          acc[gt][0] = mfma16(a0, bf, acc[gt][0]);
          acc[gt][1] = mfma16(a1, bf, acc[gt][1]);
        }
      }
      __syncthreads();             // B2: A2/XL reads done; A1 writes done
      xld_write(xv);               // XL = x_{t+2}
      __syncthreads();             // B3: XL ready
      gx_stage();                  // A2 = Gx_{t+2}
    } else {
      __syncthreads();             // B2 (final): A1 writes visible
    }
  }

  // ---------- final: out = tanh(Gh_final . W_fc^T + bfc) ----------
  {
    f32x4 oacc[2] = {{0,0,0,0},{0,0,0,0}};
    #pragma unroll 2
    for (int ks = 0; ks < 8; ks++){
      const int kk = ks*32 + g*8;
      s16x8 a0 = *(const s16x8*)&a1r[0][kk ^ swz[0]];
      s16x8 a1 = *(const s16x8*)&a1r[1][kk ^ swz[1]];
      s16x8 bf = *(const s16x8*)&WFC[u*256 + kk];
      oacc[0] = mfma16(a0, bf, oacc[0]);
      oacc[1] = mfma16(a1, bf, oacc[1]);
    }
    #pragma unroll
    for (int Mt = 0; Mt < 2; Mt++){
      int n0 = Mt*16 + g*4;
      if (n0 < 24){
        #pragma unroll
        for (int r = 0; r < 4; r++)
          out[(size_t)b*6144 + (n0+r)*256 + u] = ftanh_(oacc[Mt][r] + bfcl);
      }
    }
  }
}

extern "C" void kernel_launch(void* const* d_in, const int* in_sizes, int n_in,
                              void* d_out, int out_size, void* d_ws, size_t ws_size,
                              hipStream_t stream)
{
  (void)in_sizes; (void)n_in; (void)out_size;
  if (ws_size < WS_NEED) return;   // loud failure via validation rather than OOB

  const float* x   = (const float*)d_in[0];
  const float* G   = (const float*)d_in[1];
  const float* Wih = (const float*)d_in[2];
  const float* bih = (const float*)d_in[3];
  const float* Whh = (const float*)d_in[4];
  const float* bhh = (const float*)d_in[5];
  const float* Wh1 = (const float*)d_in[6];
  const float* bh1 = (const float*)d_in[7];
  const float* Wh2 = (const float*)d_in[8];
  const float* bh2 = (const float*)d_in[9];
  const float* Wfc = (const float*)d_in[10];
  const float* bfc = (const float*)d_in[11];
  uint8_t* ws = (uint8_t*)d_ws;

  hipLaunchKernelGGL(prep_kernel, dim3(256), dim3(256), 0, stream,
                     G, Wih, Whh, Wh1, Wh2, Wfc, ws);

  hipFuncSetAttribute((const void*)encoder_kernel,
                      hipFuncAttributeMaxDynamicSharedMemorySize, L_TOT);
  hipLaunchKernelGGL(encoder_kernel, dim3(64), dim3(1024), L_TOT, stream,
                     x, (const uint8_t*)ws, (float*)d_out,
                     bih, bhh, bh1, bh2, bfc);
}

// Round 12
// 1053.555 us; speedup vs baseline: 5137.7639x; 1.4985x over previous
//
#include <hip/hip_runtime.h>
#include <stdint.h>

#define T_ 50

typedef float f32x2 __attribute__((ext_vector_type(2)));
typedef float f32x4 __attribute__((ext_vector_type(4)));
typedef short s16x8 __attribute__((ext_vector_type(8)));

// ---------------- workspace byte offsets ----------------
// WIH/WHH packed in MFMA-fragment order:
//   off = w*16384 + gate*4096 + ks*512 + l15*32 + g*8 + j   (elems)
// WINIT packed: off = w*8192 + sel*4096 + ks*512 + l15*32 + g*8 + j
#define WS_WIH   0u          // 262144 elems
#define WS_WHH   524288u     // 262144 elems
#define WS_WINIT 1048576u    // 131072 elems
#define WS_WFC   1310720u    // [256][256] row order (one-time use)
#define WS_GPAD  1441792u    // [32][32] bf16 zero-padded G
#define WS_NEED  1443840u

// ---------------- LDS byte offsets (dynamic, 78592 B) ----------------
#define L_A1   0             // [24][256] bf16 swizzled (Gh)
#define L_A2   24576         // [24][256] bf16 swizzled (Gx)
#define L_XL   49152         // [24][260] bf16 x tile
#define L_ZR   61696         // [256] bf16 zero row
#define L_HST  62208         // [256 unit][32 node] bf16 h stage
#define L_TOT  78592

__device__ __forceinline__ f32x4 mfma16(s16x8 a, s16x8 b, f32x4 c){
  return __builtin_amdgcn_mfma_f32_16x16x32_bf16(a, b, c, 0, 0, 0);
}
__device__ __forceinline__ uint32_t bfbits(float f){
  uint32_t u = __builtin_bit_cast(uint32_t, f);
  u += 0x7FFFu + ((u >> 16) & 1u);   // RNE
  return u >> 16;
}
__device__ __forceinline__ uint32_t pk2bf(float lo, float hi){
  return bfbits(lo) | (bfbits(hi) << 16);
}
#define LOG2E 1.4426950408889634f
__device__ __forceinline__ float fexp2(float x){ return __builtin_amdgcn_exp2f(x); }
__device__ __forceinline__ float frcp_(float x){ return __builtin_amdgcn_rcpf(x); }
__device__ __forceinline__ float fsig(float x){ return frcp_(1.f + fexp2(-LOG2E * x)); }
__device__ __forceinline__ float ftanh_(float x){ return 1.f - 2.f * frcp_(1.f + fexp2(2.f * LOG2E * x)); }

// ---------------- prep: f32 -> bf16, fragment-packed ----------------
__global__ void prep_kernel(const float* __restrict__ G,
                            const float* __restrict__ Wih, const float* __restrict__ Whh,
                            const float* __restrict__ Wh1, const float* __restrict__ Wh2,
                            const float* __restrict__ Wfc, uint8_t* __restrict__ ws)
{
  const int tid = blockIdx.x * blockDim.x + threadIdx.x;
  const int nth = gridDim.x * blockDim.x;
  uint16_t* wih = (uint16_t*)(ws + WS_WIH);
  uint16_t* whh = (uint16_t*)(ws + WS_WHH);
  uint16_t* wini= (uint16_t*)(ws + WS_WINIT);
  uint16_t* wfc = (uint16_t*)(ws + WS_WFC);
  uint16_t* gp  = (uint16_t*)(ws + WS_GPAD);

  for (int i = tid; i < 262144; i += nth){
    int row = i >> 8, col = i & 255;
    int gt = row >> 8, wv = (row >> 4) & 15, l15 = row & 15;
    int ks = col >> 5, gg = (col >> 3) & 3, j = col & 7;
    int off = wv*16384 + gt*4096 + ks*512 + l15*32 + gg*8 + j;
    wih[off] = (uint16_t)bfbits(Wih[i]);
    whh[off] = (uint16_t)bfbits(Whh[i]);
  }
  for (int i = tid; i < 131072; i += nth){
    int row = i >> 8, col = i & 255;
    int sel = row >> 8, u = row & 255;
    int wv = u >> 4, l15 = u & 15;
    int ks = col >> 5, gg = (col >> 3) & 3, j = col & 7;
    int off = wv*8192 + sel*4096 + ks*512 + l15*32 + gg*8 + j;
    float v = (sel == 0) ? Wh1[u*256 + col] : Wh2[u*256 + col];
    wini[off] = (uint16_t)bfbits(v);
  }
  for (int i = tid; i < 65536; i += nth)
    wfc[i] = (uint16_t)bfbits(Wfc[i]);
  for (int i = tid; i < 1024; i += nth){
    int n = i >> 5, m = i & 31;
    gp[i] = (n < 24 && m < 24) ? (uint16_t)bfbits(G[n*24 + m]) : (uint16_t)0;
  }
}

// ---------------- one workgroup per batch, 16 waves, no inter-WG sync ----------------
__global__ void __launch_bounds__(1024, 4)
encoder_kernel(const float* __restrict__ x, const uint8_t* __restrict__ ws,
               float* __restrict__ out,
               const float* __restrict__ bih, const float* __restrict__ bhh,
               const float* __restrict__ bh1, const float* __restrict__ bh2,
               const float* __restrict__ bfc)
{
  extern __shared__ uint8_t smem[];
  uint16_t* A1  = (uint16_t*)(smem + L_A1);
  uint16_t* A2  = (uint16_t*)(smem + L_A2);
  uint16_t* XL  = (uint16_t*)(smem + L_XL);
  uint16_t* ZR  = (uint16_t*)(smem + L_ZR);
  uint16_t* HST = (uint16_t*)(smem + L_HST);

  const int tid = threadIdx.x;
  const int b   = blockIdx.x;
  const int w   = tid >> 6;        // wave 0..15
  const int l   = tid & 63;
  const int l15 = l & 15;
  const int g   = l >> 4;
  const int u   = w*16 + l15;      // unit 0..255
  const int lg  = l15*32 + g*8;    // packed-fragment lane offset

  const uint16_t* WIHW  = (const uint16_t*)(ws + WS_WIH)   + w*16384;
  const uint16_t* WHHW  = (const uint16_t*)(ws + WS_WHH)   + w*16384;
  const uint16_t* WINIW = (const uint16_t*)(ws + WS_WINIT) + w*8192;
  const uint16_t* WFC   = (const uint16_t*)(ws + WS_WFC);
  const uint16_t* GP    = (const uint16_t*)(ws + WS_GPAD);

  for (int i = tid; i < 256;  i += 1024) ZR[i] = 0;
  for (int i = tid; i < 8192; i += 1024) HST[i] = 0;   // node-pad 24-31 vs NaN

  // G A-fragments for both node tiles
  s16x8 gfragM[2];
  gfragM[0] = *(const s16x8*)&GP[(l15     )*32 + g*8];
  gfragM[1] = *(const s16x8*)&GP[(l15 + 16)*32 + g*8];

  const float bb0 = bih[u]     + bhh[u];
  const float bb1 = bih[256+u] + bhh[256+u];
  const float bb2 = bih[512+u] + bhh[512+u];
  const float bb3 = bih[768+u] + bhh[768+u];
  const float bh1l = bh1[u], bh2l = bh2[u], bfcl = bfc[u];

  // A-fragment row pointers (Mt=0 rows 0-15; Mt=1 rows 16-31, >=24 -> ZR)
  const int r1v = (16 + l15) < 24;
  const uint16_t* a1r[2] = { A1 + l15*256, r1v ? (A1 + (16+l15)*256) : ZR };
  const uint16_t* a2r[2] = { A2 + l15*256, r1v ? (A2 + (16+l15)*256) : ZR };
  const int swz[2] = { (l15 & 7) << 3, r1v ? (((16+l15) & 7) << 3) : 0 };

  // x tile: 6144 f32, 6 per thread as 3x f32x2 (issue-early/write-late)
  auto xld_issue = [&](const float* xt, f32x2 xv[3]){
    #pragma unroll
    for (int p = 0; p < 3; p++)
      xv[p] = *(const f32x2*)(xt + tid*2 + p*2048);
  };
  auto xld_write = [&](const f32x2 xv[3]){
    #pragma unroll
    for (int p = 0; p < 3; p++){
      int e = tid*2 + p*2048;
      int m = e >> 8, f = e & 255;
      *(uint32_t*)&XL[m*260 + f] = pk2bf(xv[p][0], xv[p][1]);
    }
  };

  // Gx[t]: wave's 16-feature column tile, both node tiles -> A2 swizzled
  auto gx_stage = [&](){
    s16x8 bfrag = (s16x8){0,0,0,0,0,0,0,0};
    if (g < 3){
      #pragma unroll
      for (int j = 0; j < 8; j++)
        bfrag[j] = (short)XL[(g*8 + j)*260 + u];
    }
    #pragma unroll
    for (int Mt = 0; Mt < 2; Mt++){
      f32x4 zz = {0.f,0.f,0.f,0.f};
      f32x4 gx = mfma16(gfragM[Mt], bfrag, zz);
      int n0 = Mt*16 + g*4;
      if (n0 < 24){
        uint32_t a01 = pk2bf(gx[0], gx[1]), a23 = pk2bf(gx[2], gx[3]);
        A2[(n0  )*256 + (u ^ (((n0  )&7)<<3))] = (uint16_t)a01;
        A2[(n0+1)*256 + (u ^ (((n0+1)&7)<<3))] = (uint16_t)(a01>>16);
        A2[(n0+2)*256 + (u ^ (((n0+2)&7)<<3))] = (uint16_t)a23;
        A2[(n0+3)*256 + (u ^ (((n0+3)&7)<<3))] = (uint16_t)(a23>>16);
      }
    }
  };

  // Gh from HST -> A1 swizzled
  auto gh_stage = [&](){
    s16x8 hb = *(const s16x8*)&HST[u*32 + g*8];
    #pragma unroll
    for (int Mt = 0; Mt < 2; Mt++){
      f32x4 zz = {0.f,0.f,0.f,0.f};
      f32x4 gh = mfma16(gfragM[Mt], hb, zz);
      int n0 = Mt*16 + g*4;
      if (n0 < 24){
        uint32_t a01 = pk2bf(gh[0], gh[1]), a23 = pk2bf(gh[2], gh[3]);
        A1[(n0  )*256 + (u ^ (((n0  )&7)<<3))] = (uint16_t)a01;
        A1[(n0+1)*256 + (u ^ (((n0+1)&7)<<3))] = (uint16_t)(a01>>16);
        A1[(n0+2)*256 + (u ^ (((n0+2)&7)<<3))] = (uint16_t)a23;
        A1[(n0+3)*256 + (u ^ (((n0+3)&7)<<3))] = (uint16_t)(a23>>16);
      }
    }
  };

  float cst[2][4];
  f32x4 acc[4][2];                 // [gate][node tile] — z_t, then += Gh.W_hh
  const float* xb = x + (size_t)b * T_ * 6144;

  // ---------- init ----------
  {
    f32x2 xv[3];
    xld_issue(xb, xv);
    xld_write(xv);
  }
  __syncthreads();                 // XL = x0
  gx_stage();                      // A2 = Gx0
  __syncthreads();
  {
    f32x4 h0a[2] = {{0,0,0,0},{0,0,0,0}}, c0a[2] = {{0,0,0,0},{0,0,0,0}};
    #pragma unroll
    for (int gt = 0; gt < 4; gt++)
      #pragma unroll
      for (int Mt = 0; Mt < 2; Mt++) acc[gt][Mt] = (f32x4){0,0,0,0};
    #pragma unroll 2
    for (int ks = 0; ks < 8; ks++){
      const int kk = ks*32 + g*8;
      s16x8 a0 = *(const s16x8*)&a2r[0][kk ^ swz[0]];
      s16x8 a1 = *(const s16x8*)&a2r[1][kk ^ swz[1]];
      s16x8 b1 = *(const s16x8*)&WINIW[ks*512 + lg];
      s16x8 b2 = *(const s16x8*)&WINIW[4096 + ks*512 + lg];
      h0a[0] = mfma16(a0, b1, h0a[0]);  h0a[1] = mfma16(a1, b1, h0a[1]);
      c0a[0] = mfma16(a0, b2, c0a[0]);  c0a[1] = mfma16(a1, b2, c0a[1]);
      #pragma unroll
      for (int gt = 0; gt < 4; gt++){
        s16x8 bz = *(const s16x8*)&WIHW[gt*4096 + ks*512 + lg];
        acc[gt][0] = mfma16(a0, bz, acc[gt][0]);
        acc[gt][1] = mfma16(a1, bz, acc[gt][1]);
      }
    }
    #pragma unroll
    for (int Mt = 0; Mt < 2; Mt++){
      int n0 = Mt*16 + g*4;
      float hv[4];
      #pragma unroll
      for (int r = 0; r < 4; r++){
        cst[Mt][r] = c0a[Mt][r] + bh2l;
        hv[r]      = h0a[Mt][r] + bh1l;
      }
      if (n0 < 24){
        uint2 p; p.x = pk2bf(hv[0], hv[1]); p.y = pk2bf(hv[2], hv[3]);
        *(uint2*)&HST[u*32 + n0] = p;
      }
    }
  }
  __syncthreads();                 // HST = h0; Gx0 reads done
  gh_stage();                      // A1 = Gh0
  {
    f32x2 xv[3];
    xld_issue(xb + 6144, xv);
    __syncthreads();               // XL free (x0 consumed)
    xld_write(xv);
  }
  __syncthreads();
  gx_stage();                      // A2 = Gx1
  __syncthreads();                 // A1,A2 ready

  // ---------- recurrence: acc holds z_t at loop top ----------
  for (int t = 0; t < T_; t++){
    // u = z_t + Gh_t . W_hh^T
    #pragma unroll 4
    for (int ks = 0; ks < 8; ks++){
      const int kk = ks*32 + g*8;
      s16x8 a0 = *(const s16x8*)&a1r[0][kk ^ swz[0]];
      s16x8 a1 = *(const s16x8*)&a1r[1][kk ^ swz[1]];
      #pragma unroll
      for (int gt = 0; gt < 4; gt++){
        s16x8 bf = *(const s16x8*)&WHHW[gt*4096 + ks*512 + lg];
        acc[gt][0] = mfma16(a0, bf, acc[gt][0]);
        acc[gt][1] = mfma16(a1, bf, acc[gt][1]);
      }
    }
    // LSTM pointwise -> h to HST
    #pragma unroll
    for (int Mt = 0; Mt < 2; Mt++){
      int n0 = Mt*16 + g*4;
      float hv[4];
      #pragma unroll
      for (int r = 0; r < 4; r++){
        float ig = fsig  (acc[0][Mt][r] + bb0);
        float fg = fsig  (acc[1][Mt][r] + bb1);
        float gg = ftanh_(acc[2][Mt][r] + bb2);
        float og = fsig  (acc[3][Mt][r] + bb3);
        float c  = fg*cst[Mt][r] + ig*gg;
        cst[Mt][r] = c;
        hv[r] = og*ftanh_(c);
      }
      if (n0 < 24){
        uint2 p; p.x = pk2bf(hv[0], hv[1]); p.y = pk2bf(hv[2], hv[3]);
        *(uint2*)&HST[u*32 + n0] = p;
      }
    }
    __syncthreads();               // B1: HST done; A1 reads done
    gh_stage();                    // A1 = Gh_{t+1}

    if (t+1 < T_){
      int tn = (t+2 < T_) ? (t+2) : (T_-1);
      f32x2 xv[3];
      xld_issue(xb + (size_t)tn*6144, xv);   // x_{t+2}, hides under z-GEMM
      // z_{t+1} = Gx_{t+1} . W_ih^T
      #pragma unroll
      for (int gt = 0; gt < 4; gt++)
        #pragma unroll
        for (int Mt = 0; Mt < 2; Mt++) acc[gt][Mt] = (f32x4){0,0,0,0};
      #pragma unroll 4
      for (int ks = 0; ks < 8; ks++){
        const int kk = ks*32 + g*8;
        s16x8 a0 = *(const s16x8*)&a2r[0][kk ^ swz[0]];
        s16x8 a1 = *(const s16x8*)&a2r[1][kk ^ swz[1]];
        #pragma unroll
        for (int gt = 0; gt < 4; gt++){
          s16x8 bf = *(const s16x8*)&WIHW[gt*4096 + ks*512 + lg];
          acc[gt][0] = mfma16(a0, bf, acc[gt][0]);
          acc[gt][1] = mfma16(a1, bf, acc[gt][1]);
        }
      }
      __syncthreads();             // B2: A2/XL reads done; A1 writes done
      xld_write(xv);               // XL = x_{t+2}
      __syncthreads();             // B3: XL ready
      gx_stage();                  // A2 = Gx_{t+2}
    } else {
      __syncthreads();             // B2 (final): A1 writes visible
    }
  }

  // ---------- final: out = tanh(Gh_final . W_fc^T + bfc) ----------
  {
    f32x4 oacc[2] = {{0,0,0,0},{0,0,0,0}};
    #pragma unroll 2
    for (int ks = 0; ks < 8; ks++){
      const int kk = ks*32 + g*8;
      s16x8 a0 = *(const s16x8*)&a1r[0][kk ^ swz[0]];
      s16x8 a1 = *(const s16x8*)&a1r[1][kk ^ swz[1]];
      s16x8 bf = *(const s16x8*)&WFC[u*256 + kk];
      oacc[0] = mfma16(a0, bf, oacc[0]);
      oacc[1] = mfma16(a1, bf, oacc[1]);
    }
    #pragma unroll
    for (int Mt = 0; Mt < 2; Mt++){
      int n0 = Mt*16 + g*4;
      if (n0 < 24){
        #pragma unroll
        for (int r = 0; r < 4; r++)
          out[(size_t)b*6144 + (n0+r)*256 + u] = ftanh_(oacc[Mt][r] + bfcl);
      }
    }
  }
}

extern "C" void kernel_launch(void* const* d_in, const int* in_sizes, int n_in,
                              void* d_out, int out_size, void* d_ws, size_t ws_size,
                              hipStream_t stream)
{
  (void)in_sizes; (void)n_in; (void)out_size;
  if (ws_size < WS_NEED) return;   // loud failure via validation rather than OOB

  const float* x   = (const float*)d_in[0];
  const float* G   = (const float*)d_in[1];
  const float* Wih = (const float*)d_in[2];
  const float* bih = (const float*)d_in[3];
  const float* Whh = (const float*)d_in[4];
  const float* bhh = (const float*)d_in[5];
  const float* Wh1 = (const float*)d_in[6];
  const float* bh1 = (const float*)d_in[7];
  const float* Wh2 = (const float*)d_in[8];
  const float* bh2 = (const float*)d_in[9];
  const float* Wfc = (const float*)d_in[10];
  const float* bfc = (const float*)d_in[11];
  uint8_t* ws = (uint8_t*)d_ws;

  hipLaunchKernelGGL(prep_kernel, dim3(256), dim3(256), 0, stream,
                     G, Wih, Whh, Wh1, Wh2, Wfc, ws);

  hipFuncSetAttribute((const void*)encoder_kernel,
                      hipFuncAttributeMaxDynamicSharedMemorySize, L_TOT);
  hipLaunchKernelGGL(encoder_kernel, dim3(64), dim3(1024), L_TOT, stream,
                     x, (const uint8_t*)ws, (float*)d_out,
                     bih, bhh, bh1, bh2, bfc);
}